// Round 9
// baseline (395.159 us; speedup 1.0000x reference)
//
#include <hip/hip_runtime.h>
#include <hip/hip_bf16.h>
#include <math.h>

#define D_MODEL 1024
#define N_HEADS 16
#define D_K     64
#define S_LEN   2048
#define B_SZ    2

typedef unsigned short u16;
typedef unsigned int   u32;
using short8 = __attribute__((ext_vector_type(8))) short;
using f32x4  = __attribute__((ext_vector_type(4))) float;

__device__ inline float bf2f(u16 u) { return __uint_as_float((u32)u << 16); }
__device__ inline u16 f2bf(float f) {
    __hip_bfloat16 h = __float2bfloat16(f);   // RNE
    return *(u16*)&h;
}
__device__ inline u32 pkbf(float lo, float hi) {
    return ((u32)f2bf(hi) << 16) | f2bf(lo);
}
__device__ inline void gload_lds16(const void* g, void* l) {
    __builtin_amdgcn_global_load_lds(
        (const __attribute__((address_space(1))) unsigned int*)g,
        (__attribute__((address_space(3))) unsigned int*)l, 16, 0, 0);
}

// ---------------------------------------------------------------------------
// Fused fp32->bf16 cast of x, W_qkv, W_out (one launch).
// ---------------------------------------------------------------------------
#define N1 (B_SZ * S_LEN * D_MODEL / 4)
#define N2 (3 * D_MODEL * D_MODEL / 4)
#define N3 (D_MODEL * D_MODEL / 4)

__global__ __launch_bounds__(256)
void cast3_f32_bf16(const float* __restrict__ x, const float* __restrict__ wq,
                    const float* __restrict__ wo, u16* __restrict__ xb,
                    u16* __restrict__ wqb, u16* __restrict__ wob) {
    int i = blockIdx.x * 256 + threadIdx.x;
    const float4* src;
    ushort4* dst;
    if (i < N1)            { src = (const float4*)x  + i;             dst = (ushort4*)xb  + i; }
    else if (i < N1 + N2)  { src = (const float4*)wq + (i - N1);      dst = (ushort4*)wqb + (i - N1); }
    else                   { src = (const float4*)wo + (i - N1 - N2); dst = (ushort4*)wob + (i - N1 - N2); }
    float4 v = *src;
    ushort4 u;
    u.x = f2bf(v.x); u.y = f2bf(v.y); u.z = f2bf(v.z); u.w = f2bf(v.w);
    *dst = u;
}

// ---------------------------------------------------------------------------
// bf16 MFMA GEMM (m97 structure): C[M][N] = A[M][K] * B[N][K]^T. (R2-verified,
// plain epilogue — the R7 fused-RoPE epilogue cost +35 µs and was reverted.)
// ---------------------------------------------------------------------------
template <bool OUT_BF16>
__global__ __launch_bounds__(256)
void gemm_bt_mfma(const u16* __restrict__ A, const u16* __restrict__ B,
                  void* __restrict__ Cout, int M, int N, int K) {
    __shared__ u16 As[128 * 32];
    __shared__ u16 Bs[128 * 32];
    const int tid  = threadIdx.x;
    const int lane = tid & 63;
    const int wv   = tid >> 6;
    const int wm   = wv >> 1, wn = wv & 1;
    const int row0 = blockIdx.y * 128;
    const int col0 = blockIdx.x * 128;

    const int lr = lane >> 2;
    const int lc = (lane & 3) * 8;

    f32x4 acc[4][4] = {};

    for (int k0 = 0; k0 < K; k0 += 32) {
#pragma unroll
        for (int t = 0; t < 2; t++) {
            int rblk = wv * 32 + t * 16;
            gload_lds16(A + (size_t)(row0 + rblk + lr) * K + k0 + lc, &As[rblk * 32]);
            gload_lds16(B + (size_t)(col0 + rblk + lr) * K + k0 + lc, &Bs[rblk * 32]);
        }
        __syncthreads();

        short8 af[4], bfr[4];
#pragma unroll
        for (int mi = 0; mi < 4; mi++)
            af[mi] = *(const short8*)&As[(wm * 64 + mi * 16 + (lane & 15)) * 32 + (lane >> 4) * 8];
#pragma unroll
        for (int nj = 0; nj < 4; nj++)
            bfr[nj] = *(const short8*)&Bs[(wn * 64 + nj * 16 + (lane & 15)) * 32 + (lane >> 4) * 8];
#pragma unroll
        for (int mi = 0; mi < 4; mi++)
#pragma unroll
            for (int nj = 0; nj < 4; nj++)
                acc[mi][nj] = __builtin_amdgcn_mfma_f32_16x16x32_bf16(
                    af[mi], bfr[nj], acc[mi][nj], 0, 0, 0);
        __syncthreads();
    }

    const int cr = (lane >> 4) * 4;
    const int cc = lane & 15;
#pragma unroll
    for (int mi = 0; mi < 4; mi++) {
#pragma unroll
        for (int nj = 0; nj < 4; nj++) {
            int c = col0 + wn * 64 + nj * 16 + cc;
#pragma unroll
            for (int r = 0; r < 4; r++) {
                int rr = row0 + wm * 64 + mi * 16 + cr + r;
                if (OUT_BF16)
                    ((u16*)Cout)[(size_t)rr * N + c] = f2bf(acc[mi][nj][r]);
                else
                    ((float*)Cout)[(size_t)rr * N + c] = acc[mi][nj][r];
            }
        }
    }
}

// ---------------------------------------------------------------------------
// RoPE in place on bf16 qkv Q/K slices. Q scaled by (1/8)*log2(e) for
// exp2-based softmax downstream. (Standalone kernel — ~10 µs, proven.)
// ---------------------------------------------------------------------------
__global__ __launch_bounds__(256)
void rope_bf16(u16* __restrict__ qkv, const int* __restrict__ pos) {
    int idx = blockIdx.x * blockDim.x + threadIdx.x;
    int j = idx & 31;
    int h = (idx >> 5) & 15;
    int w = (idx >> 9) & 1;
    int s = (idx >> 10) & 2047;
    int b = idx >> 21;

    float p = (float)pos[s];
    float inv_freq = __powf(10000.0f, -(float)(2 * j) / 64.0f);
    float ang = p * inv_freq;
    float sn, cs;
    sincosf(ang, &sn, &cs);
    float sc = (w == 0) ? 0.125f * 1.44269504f : 1.0f;

    size_t base = (((size_t)(b * S_LEN + s) * 3 + w) * D_MODEL) + h * D_K + 2 * j;
    float x1 = bf2f(qkv[base]);
    float x2 = bf2f(qkv[base + 1]);
    qkv[base]     = f2bf((x1 * cs - x2 * sn) * sc);
    qkv[base + 1] = f2bf((x1 * sn + x2 * cs) * sc);
}

// ---------------------------------------------------------------------------
// V transpose: qkv V slice (B,S,3,H,D) -> VT (B,H,D,S). Coalesced via LDS.
// ---------------------------------------------------------------------------
__global__ __launch_bounds__(256)
void vtrans(const u16* __restrict__ qkv, u16* __restrict__ VT) {
    __shared__ u16 t[64][68];
    const int st = blockIdx.x, h = blockIdx.y, b = blockIdx.z;
    const int tid = threadIdx.x;
    const int bh = b * N_HEADS + h;

#pragma unroll
    for (int i = 0; i < 4; i++) {
        int e  = tid + i * 256;
        int sl = e >> 4;
        int c4 = e & 15;
        ushort4 v = *(const ushort4*)&qkv[((size_t)(b * S_LEN + st * 64 + sl) * 3 + 2) * D_MODEL
                                          + h * D_K + c4 * 4];
        *(ushort4*)&t[sl][c4 * 4] = v;
    }
    __syncthreads();
#pragma unroll
    for (int i = 0; i < 4; i++) {
        int e  = tid + i * 256;
        int d  = e >> 4;
        int s4 = e & 15;
        ushort4 o;
        o.x = t[s4 * 4 + 0][d];
        o.y = t[s4 * 4 + 1][d];
        o.z = t[s4 * 4 + 2][d];
        o.w = t[s4 * 4 + 3][d];
        *(ushort4*)&VT[((size_t)bh * D_K + d) * S_LEN + st * 64 + s4 * 4] = o;
    }
}

// ---------------------------------------------------------------------------
// MFMA flash attention v6 (causal): BARRIER-FREE. 4 waves per (b,h,64-q
// tile); wave owns 16 queries, loops its k-tiles independently.
// K and V fragments are loaded DIRECTLY from global (L2-resident: 512 KB
// per (b,h), reused by all 32 q-blocks) as 16B vector loads already in
// A-operand layout — no LDS staging, no __syncthreads, no vmcnt(0) drains.
// Only the wave-private P strip round-trips LDS (8.7 KB total).
// S^T = K·Q^T (C: row=key, col=query=l15); O^T accumulation (in-lane
// alpha/invl, zero shuffles); softmax base-2 (Q pre-scaled by 0.125*log2e).
// ---------------------------------------------------------------------------
__global__ __launch_bounds__(256)
void attn_mfma(const u16* __restrict__ qkv, const u16* __restrict__ VT,
               u16* __restrict__ out) {
    __shared__ u16 Ps[4][16 * 68];    // per-wave [query 16][key 64 + pad]

    const int tid  = threadIdx.x;
    const int lane = tid & 63;
    const int wv   = tid >> 6;
    const int qt   = gridDim.x - 1 - blockIdx.x;   // longest blocks first
    const int h    = blockIdx.y, b = blockIdx.z;
    const int bh   = b * N_HEADS + h;
    const int qw0  = qt * 64 + wv * 16;            // this wave's first query
    const int l15  = lane & 15;
    const int quad = lane >> 4;

    const size_t vtb = (size_t)bh * D_K * S_LEN;
    u16* Psw = &Ps[wv][0];

    // Q fragments (B-operand layout [n=query l15][k=d quad*8+j]); pre-scaled.
    short8 qf[2];
#pragma unroll
    for (int kf = 0; kf < 2; kf++)
        qf[kf] = *(const short8*)&qkv[((size_t)(b * S_LEN + qw0 + l15) * 3 + 0) * D_MODEL
                                      + h * D_K + kf * 32 + quad * 8];

    f32x4 accT[4] = {};   // O^T: d = nj*16 + quad*4 + r, query = l15
    float mq = -INFINITY;
    float lq = 0.f;

    for (int kt = 0; kt <= qt; kt++) {
        const int k0 = kt * 64;

        // ---- K fragments direct from global (A-layout [m=key][k=d]) ----
        short8 kfr[2][4];
#pragma unroll
        for (int kf = 0; kf < 2; kf++)
#pragma unroll
            for (int nj = 0; nj < 4; nj++)
                kfr[kf][nj] = *(const short8*)&qkv[
                    ((size_t)(b * S_LEN + k0 + nj * 16 + l15) * 3 + 1) * D_MODEL
                    + h * D_K + kf * 32 + quad * 8];

        // ---- S^T = K·Q^T : rows=keys (quad*4+r), col=query (l15) ----
        f32x4 s[4] = {};
#pragma unroll
        for (int kf = 0; kf < 2; kf++)
#pragma unroll
            for (int nj = 0; nj < 4; nj++)
                s[nj] = __builtin_amdgcn_mfma_f32_16x16x32_bf16(
                    kfr[kf][nj], qf[kf], s[nj], 0, 0, 0);

        // ---- V^T fragments direct from global (A-layout [m=d][k=key]);
        //      issued here so their latency overlaps the softmax ----
        short8 vf[2][4];
#pragma unroll
        for (int kf = 0; kf < 2; kf++)
#pragma unroll
            for (int nj = 0; nj < 4; nj++)
                vf[kf][nj] = *(const short8*)&VT[
                    vtb + (size_t)(nj * 16 + l15) * S_LEN + k0 + kf * 32 + quad * 8];

        // ---- causal mask (diagonal tile only) ----
        if (kt == qt) {
            const int row_g = qw0 + l15;
#pragma unroll
            for (int nj = 0; nj < 4; nj++)
#pragma unroll
                for (int r = 0; r < 4; r++) {
                    int key_g = k0 + nj * 16 + quad * 4 + r;
                    if (key_g > row_g) s[nj][r] = -INFINITY;
                }
        }

        // ---- online softmax (base 2): one query per lane ----
        float rmax = s[0][0];
#pragma unroll
        for (int nj = 0; nj < 4; nj++)
#pragma unroll
            for (int r = 0; r < 4; r++) rmax = fmaxf(rmax, s[nj][r]);
        rmax = fmaxf(rmax, __shfl_xor(rmax, 16, 64));
        rmax = fmaxf(rmax, __shfl_xor(rmax, 32, 64));
        float mn = fmaxf(mq, rmax);
        float alpha = exp2f(mq - mn);
        mq = mn;
        float rsum = 0.f;
#pragma unroll
        for (int nj = 0; nj < 4; nj++)
#pragma unroll
            for (int r = 0; r < 4; r++) {
                float p = exp2f(s[nj][r] - mn);
                s[nj][r] = p;
                rsum += p;
            }
        rsum += __shfl_xor(rsum, 16, 64);
        rsum += __shfl_xor(rsum, 32, 64);
        lq = lq * alpha + rsum;

        // ---- rescale O^T in-lane ----
#pragma unroll
        for (int nj = 0; nj < 4; nj++)
#pragma unroll
            for (int r = 0; r < 4; r++) accT[nj][r] *= alpha;

        // ---- P (bf16 pairs) -> wave-private LDS strip [query][key] ----
#pragma unroll
        for (int nj = 0; nj < 4; nj++) {
            uint2 pk;
            pk.x = pkbf(s[nj][0], s[nj][1]);
            pk.y = pkbf(s[nj][2], s[nj][3]);
            *(uint2*)&Psw[l15 * 68 + nj * 16 + quad * 4] = pk;
        }
        // same-wave LDS RAW -> compiler inserts lgkmcnt wait

        // ---- O^T += V^T·P^T : A=vf[m=d][k=key], B=P[n=query][k=key] ----
#pragma unroll
        for (int kf = 0; kf < 2; kf++) {
            const u16* pp = &Psw[l15 * 68 + kf * 32 + quad * 8];
            uint2 plo = *(const uint2*)pp;
            uint2 phi = *(const uint2*)(pp + 4);
            u32 praw[4] = { plo.x, plo.y, phi.x, phi.y };
            short8 pf = *(const short8*)praw;
#pragma unroll
            for (int nj = 0; nj < 4; nj++)
                accT[nj] = __builtin_amdgcn_mfma_f32_16x16x32_bf16(
                    vf[kf][nj], pf, accT[nj], 0, 0, 0);
        }
    }

    // ---- epilogue: normalize in-lane, store 4 consecutive d per uint2 ----
    float invl = 1.f / lq;
    const size_t obase = (size_t)(b * S_LEN + qw0 + l15) * D_MODEL + h * D_K;
#pragma unroll
    for (int nj = 0; nj < 4; nj++) {
        uint2 pk;
        pk.x = pkbf(accT[nj][0] * invl, accT[nj][1] * invl);
        pk.y = pkbf(accT[nj][2] * invl, accT[nj][3] * invl);
        *(uint2*)&out[obase + nj * 16 + quad * 4] = pk;
    }
}

// ---------------------------------------------------------------------------
extern "C" void kernel_launch(void* const* d_in, const int* in_sizes, int n_in,
                              void* d_out, int out_size, void* d_ws, size_t ws_size,
                              hipStream_t stream) {
    const float* x    = (const float*)d_in[0];
    const int*   pos  = (const int*)d_in[1];
    const float* Wqkv = (const float*)d_in[2];
    const float* Wout = (const float*)d_in[3];
    float*       out  = (float*)d_out;

    const int M = B_SZ * S_LEN;   // 4096

    u16* qkvb = (u16*)d_ws;                            // 4096 x 3072
    u16* aob  = qkvb + (size_t)M * 3 * D_MODEL;        // 4096 x 1024
    u16* xb   = aob  + (size_t)M * D_MODEL;            // 4096 x 1024
    u16* wqb  = xb   + (size_t)M * D_MODEL;            // 3072 x 1024
    u16* wob  = wqb  + (size_t)3 * D_MODEL * D_MODEL;  // 1024 x 1024
    u16* vtb  = wob  + (size_t)D_MODEL * D_MODEL;      // 4096 x 1024 (B,H,D,S)

    // 0) fused casts
    cast3_f32_bf16<<<(N1 + N2 + N3) / 256, 256, 0, stream>>>(x, Wqkv, Wout, xb, wqb, wob);

    // 1) qkv = x @ W_qkv^T
    gemm_bt_mfma<true><<<dim3(3 * D_MODEL / 128, M / 128), 256, 0, stream>>>(
        xb, wqb, qkvb, M, 3 * D_MODEL, D_MODEL);

    // 2) RoPE in place (Q scaled by 0.125*log2e)
    rope_bf16<<<(B_SZ * S_LEN * 2 * N_HEADS * 32) / 256, 256, 0, stream>>>(qkvb, pos);

    // 3) V transpose -> (B,H,D,S)
    vtrans<<<dim3(S_LEN / 64, N_HEADS, B_SZ), 256, 0, stream>>>(qkvb, vtb);

    // 4) barrier-free MFMA flash attention -> aob (B,S,H*D) bf16
    attn_mfma<<<dim3(S_LEN / 64, N_HEADS, B_SZ), 256, 0, stream>>>(qkvb, vtb, aob);

    // 5) out = ao @ W_out^T (fp32 out)
    gemm_bt_mfma<false><<<dim3(D_MODEL / 128, M / 128), 256, 0, stream>>>(
        aob, wob, out, M, D_MODEL, D_MODEL);
}

// Round 10
// 253.017 us; speedup vs baseline: 1.5618x; 1.5618x over previous
//
#include <hip/hip_runtime.h>
#include <hip/hip_bf16.h>
#include <math.h>

#define D_MODEL 1024
#define N_HEADS 16
#define D_K     64
#define S_LEN   2048
#define B_SZ    2

typedef unsigned short u16;
typedef unsigned int   u32;
using short8 = __attribute__((ext_vector_type(8))) short;
using f32x4  = __attribute__((ext_vector_type(4))) float;

__device__ inline float bf2f(u16 u) { return __uint_as_float((u32)u << 16); }
__device__ inline u16 f2bf(float f) {
    __hip_bfloat16 h = __float2bfloat16(f);   // RNE
    return *(u16*)&h;
}
__device__ inline u32 pkbf(float lo, float hi) {
    return ((u32)f2bf(hi) << 16) | f2bf(lo);
}
__device__ inline void gload_lds16(const void* g, void* l) {
    __builtin_amdgcn_global_load_lds(
        (const __attribute__((address_space(1))) unsigned int*)g,
        (__attribute__((address_space(3))) unsigned int*)l, 16, 0, 0);
}

// ---------------------------------------------------------------------------
// Fused fp32->bf16 cast of x, W_qkv, W_out (one launch).
// ---------------------------------------------------------------------------
#define N1 (B_SZ * S_LEN * D_MODEL / 4)
#define N2 (3 * D_MODEL * D_MODEL / 4)
#define N3 (D_MODEL * D_MODEL / 4)

__global__ __launch_bounds__(256)
void cast3_f32_bf16(const float* __restrict__ x, const float* __restrict__ wq,
                    const float* __restrict__ wo, u16* __restrict__ xb,
                    u16* __restrict__ wqb, u16* __restrict__ wob) {
    int i = blockIdx.x * 256 + threadIdx.x;
    const float4* src;
    ushort4* dst;
    if (i < N1)            { src = (const float4*)x  + i;             dst = (ushort4*)xb  + i; }
    else if (i < N1 + N2)  { src = (const float4*)wq + (i - N1);      dst = (ushort4*)wqb + (i - N1); }
    else                   { src = (const float4*)wo + (i - N1 - N2); dst = (ushort4*)wob + (i - N1 - N2); }
    float4 v = *src;
    ushort4 u;
    u.x = f2bf(v.x); u.y = f2bf(v.y); u.z = f2bf(v.z); u.w = f2bf(v.w);
    *dst = u;
}

// ---------------------------------------------------------------------------
// bf16 MFMA GEMM (m97 structure): C[M][N] = A[M][K] * B[N][K]^T. (R2-verified,
// plain epilogue. Fused-RoPE epilogue (R7) cost +35 µs — keep it out.)
// ---------------------------------------------------------------------------
template <bool OUT_BF16>
__global__ __launch_bounds__(256)
void gemm_bt_mfma(const u16* __restrict__ A, const u16* __restrict__ B,
                  void* __restrict__ Cout, int M, int N, int K) {
    __shared__ u16 As[128 * 32];
    __shared__ u16 Bs[128 * 32];
    const int tid  = threadIdx.x;
    const int lane = tid & 63;
    const int wv   = tid >> 6;
    const int wm   = wv >> 1, wn = wv & 1;
    const int row0 = blockIdx.y * 128;
    const int col0 = blockIdx.x * 128;

    const int lr = lane >> 2;
    const int lc = (lane & 3) * 8;

    f32x4 acc[4][4] = {};

    for (int k0 = 0; k0 < K; k0 += 32) {
#pragma unroll
        for (int t = 0; t < 2; t++) {
            int rblk = wv * 32 + t * 16;
            gload_lds16(A + (size_t)(row0 + rblk + lr) * K + k0 + lc, &As[rblk * 32]);
            gload_lds16(B + (size_t)(col0 + rblk + lr) * K + k0 + lc, &Bs[rblk * 32]);
        }
        __syncthreads();

        short8 af[4], bfr[4];
#pragma unroll
        for (int mi = 0; mi < 4; mi++)
            af[mi] = *(const short8*)&As[(wm * 64 + mi * 16 + (lane & 15)) * 32 + (lane >> 4) * 8];
#pragma unroll
        for (int nj = 0; nj < 4; nj++)
            bfr[nj] = *(const short8*)&Bs[(wn * 64 + nj * 16 + (lane & 15)) * 32 + (lane >> 4) * 8];
#pragma unroll
        for (int mi = 0; mi < 4; mi++)
#pragma unroll
            for (int nj = 0; nj < 4; nj++)
                acc[mi][nj] = __builtin_amdgcn_mfma_f32_16x16x32_bf16(
                    af[mi], bfr[nj], acc[mi][nj], 0, 0, 0);
        __syncthreads();
    }

    const int cr = (lane >> 4) * 4;
    const int cc = lane & 15;
#pragma unroll
    for (int mi = 0; mi < 4; mi++) {
#pragma unroll
        for (int nj = 0; nj < 4; nj++) {
            int c = col0 + wn * 64 + nj * 16 + cc;
#pragma unroll
            for (int r = 0; r < 4; r++) {
                int rr = row0 + wm * 64 + mi * 16 + cr + r;
                if (OUT_BF16)
                    ((u16*)Cout)[(size_t)rr * N + c] = f2bf(acc[mi][nj][r]);
                else
                    ((float*)Cout)[(size_t)rr * N + c] = acc[mi][nj][r];
            }
        }
    }
}

// ---------------------------------------------------------------------------
// RoPE in place on bf16 qkv Q/K slices. Q scaled by (1/8)*log2(e) for
// exp2-based softmax downstream.
// ---------------------------------------------------------------------------
__global__ __launch_bounds__(256)
void rope_bf16(u16* __restrict__ qkv, const int* __restrict__ pos) {
    int idx = blockIdx.x * blockDim.x + threadIdx.x;
    int j = idx & 31;
    int h = (idx >> 5) & 15;
    int w = (idx >> 9) & 1;
    int s = (idx >> 10) & 2047;
    int b = idx >> 21;

    float p = (float)pos[s];
    float inv_freq = __powf(10000.0f, -(float)(2 * j) / 64.0f);
    float ang = p * inv_freq;
    float sn, cs;
    sincosf(ang, &sn, &cs);
    float sc = (w == 0) ? 0.125f * 1.44269504f : 1.0f;

    size_t base = (((size_t)(b * S_LEN + s) * 3 + w) * D_MODEL) + h * D_K + 2 * j;
    float x1 = bf2f(qkv[base]);
    float x2 = bf2f(qkv[base + 1]);
    qkv[base]     = f2bf((x1 * cs - x2 * sn) * sc);
    qkv[base + 1] = f2bf((x1 * sn + x2 * cs) * sc);
}

// ---------------------------------------------------------------------------
// V transpose: qkv V slice (B,S,3,H,D) -> VT (B,H,D,S). Coalesced via LDS.
// ---------------------------------------------------------------------------
__global__ __launch_bounds__(256)
void vtrans(const u16* __restrict__ qkv, u16* __restrict__ VT) {
    __shared__ u16 t[64][68];
    const int st = blockIdx.x, h = blockIdx.y, b = blockIdx.z;
    const int tid = threadIdx.x;
    const int bh = b * N_HEADS + h;

#pragma unroll
    for (int i = 0; i < 4; i++) {
        int e  = tid + i * 256;
        int sl = e >> 4;
        int c4 = e & 15;
        ushort4 v = *(const ushort4*)&qkv[((size_t)(b * S_LEN + st * 64 + sl) * 3 + 2) * D_MODEL
                                          + h * D_K + c4 * 4];
        *(ushort4*)&t[sl][c4 * 4] = v;
    }
    __syncthreads();
#pragma unroll
    for (int i = 0; i < 4; i++) {
        int e  = tid + i * 256;
        int d  = e >> 4;
        int s4 = e & 15;
        ushort4 o;
        o.x = t[s4 * 4 + 0][d];
        o.y = t[s4 * 4 + 1][d];
        o.z = t[s4 * 4 + 2][d];
        o.w = t[s4 * 4 + 3][d];
        *(ushort4*)&VT[((size_t)bh * D_K + d) * S_LEN + st * 64 + s4 * 4] = o;
    }
}

// ---------------------------------------------------------------------------
// MFMA flash attention v5 (causal) — best measured structure (R7):
// single-buffered LDS staging via global_load_lds (the coalescer — R8's
// direct-global loads shattered into scattered L2 transactions and lost 3x),
// 25 KB LDS -> 4 blocks/CU, S^T = K·Q^T (C: row=key, col=query=l15) so
// softmax stats are per-lane, O^T accumulation (in-lane alpha/invl, zero
// shuffles), exp2 softmax (Q pre-scaled by 0.125*log2e).
// ---------------------------------------------------------------------------
__global__ __launch_bounds__(256)
void attn_mfma(const u16* __restrict__ qkv, const u16* __restrict__ VT,
               u16* __restrict__ out) {
    __shared__ u16 Ks[2][64 * 32];    // [kf d-chunk][key*32 + dL]
    __shared__ u16 VsT[2][64 * 32];   // [kc key-chunk][d*32 + kL]
    __shared__ u16 Ps[4][16 * 68];    // per-wave [query 16][key 64 + pad]
    // total 25088 B -> 4 blocks/CU

    const int tid  = threadIdx.x;
    const int lane = tid & 63;
    const int wv   = tid >> 6;
    const int qt   = gridDim.x - 1 - blockIdx.x;   // longest blocks first
    const int h    = blockIdx.y, b = blockIdx.z;
    const int bh   = b * N_HEADS + h;
    const int qw0  = qt * 64 + wv * 16;
    const int l15  = lane & 15;
    const int quad = lane >> 4;
    const int lr   = lane >> 2;
    const int lc   = (lane & 3) * 8;

    const size_t vtb = (size_t)bh * D_K * S_LEN;
    u16* Psw = &Ps[wv][0];

    // Q fragments (B-operand layout [n=query l15][k=d quad*8+j]); pre-scaled.
    short8 qf[2];
#pragma unroll
    for (int kf = 0; kf < 2; kf++)
        qf[kf] = *(const short8*)&qkv[((size_t)(b * S_LEN + qw0 + l15) * 3 + 0) * D_MODEL
                                      + h * D_K + kf * 32 + quad * 8];

    f32x4 accT[4] = {};   // O^T: d = nj*16 + quad*4 + r, query = l15
    float mq = -INFINITY;
    float lq = 0.f;

    for (int kt = 0; kt <= qt; kt++) {
        const int k0 = kt * 64;
        __syncthreads();   // all waves done reading LDS tile t-1

        // ---- DMA this tile into LDS (coalesced: lane-contiguous dest) ----
#pragma unroll
        for (int kf = 0; kf < 2; kf++)
            gload_lds16(qkv + ((size_t)(b * S_LEN + k0 + wv * 16 + lr) * 3 + 1) * D_MODEL
                            + h * D_K + kf * 32 + lc,
                        &Ks[kf][(wv * 16) * 32]);
#pragma unroll
        for (int kc = 0; kc < 2; kc++)
            gload_lds16(VT + vtb + (size_t)(wv * 16 + lr) * S_LEN + k0 + kc * 32 + lc,
                        &VsT[kc][(wv * 16) * 32]);
        __syncthreads();   // vmcnt(0) drain -> tile resident

        if (k0 > qw0 + 15) continue;   // wave fully above diagonal

        // ---- S^T = K·Q^T : rows=keys (quad*4+r), col=query (l15) ----
        f32x4 s[4] = {};
#pragma unroll
        for (int kf = 0; kf < 2; kf++)
#pragma unroll
            for (int nj = 0; nj < 4; nj++) {
                short8 kfr = *(const short8*)&Ks[kf][(nj * 16 + l15) * 32 + quad * 8];
                s[nj] = __builtin_amdgcn_mfma_f32_16x16x32_bf16(kfr, qf[kf], s[nj], 0, 0, 0);
            }

        // ---- causal mask (diagonal tile only) ----
        if (kt == qt) {
            const int row_g = qw0 + l15;
#pragma unroll
            for (int nj = 0; nj < 4; nj++)
#pragma unroll
                for (int r = 0; r < 4; r++) {
                    int key_g = k0 + nj * 16 + quad * 4 + r;
                    if (key_g > row_g) s[nj][r] = -INFINITY;
                }
        }

        // ---- online softmax (base 2): one query per lane ----
        float rmax = s[0][0];
#pragma unroll
        for (int nj = 0; nj < 4; nj++)
#pragma unroll
            for (int r = 0; r < 4; r++) rmax = fmaxf(rmax, s[nj][r]);
        rmax = fmaxf(rmax, __shfl_xor(rmax, 16, 64));
        rmax = fmaxf(rmax, __shfl_xor(rmax, 32, 64));
        float mn = fmaxf(mq, rmax);
        float alpha = exp2f(mq - mn);
        mq = mn;
        float rsum = 0.f;
#pragma unroll
        for (int nj = 0; nj < 4; nj++)
#pragma unroll
            for (int r = 0; r < 4; r++) {
                float p = exp2f(s[nj][r] - mn);
                s[nj][r] = p;
                rsum += p;
            }
        rsum += __shfl_xor(rsum, 16, 64);
        rsum += __shfl_xor(rsum, 32, 64);
        lq = lq * alpha + rsum;

        // ---- rescale O^T in-lane (alpha lives at col=query=l15) ----
#pragma unroll
        for (int nj = 0; nj < 4; nj++)
#pragma unroll
            for (int r = 0; r < 4; r++) accT[nj][r] *= alpha;

        // ---- P (bf16 pairs) -> wave-private LDS strip [query][key] ----
#pragma unroll
        for (int nj = 0; nj < 4; nj++) {
            uint2 pk;
            pk.x = pkbf(s[nj][0], s[nj][1]);
            pk.y = pkbf(s[nj][2], s[nj][3]);
            *(uint2*)&Psw[l15 * 68 + nj * 16 + quad * 4] = pk;
        }
        // same-wave LDS RAW -> compiler inserts lgkmcnt wait

        // ---- O^T += V^T·P^T : A=VsT[m=d][k=key], B=P[n=query][k=key] ----
#pragma unroll
        for (int kf = 0; kf < 2; kf++) {
            const u16* pp = &Psw[l15 * 68 + kf * 32 + quad * 8];
            uint2 plo = *(const uint2*)pp;
            uint2 phi = *(const uint2*)(pp + 4);
            u32 praw[4] = { plo.x, plo.y, phi.x, phi.y };
            short8 pf = *(const short8*)praw;
#pragma unroll
            for (int nj = 0; nj < 4; nj++) {
                short8 vf = *(const short8*)&VsT[kf][(nj * 16 + l15) * 32 + quad * 8];
                accT[nj] = __builtin_amdgcn_mfma_f32_16x16x32_bf16(vf, pf, accT[nj], 0, 0, 0);
            }
        }
    }

    // ---- epilogue: normalize in-lane, store 4 consecutive d per uint2 ----
    float invl = 1.f / lq;
    const size_t obase = (size_t)(b * S_LEN + qw0 + l15) * D_MODEL + h * D_K;
#pragma unroll
    for (int nj = 0; nj < 4; nj++) {
        uint2 pk;
        pk.x = pkbf(accT[nj][0] * invl, accT[nj][1] * invl);
        pk.y = pkbf(accT[nj][2] * invl, accT[nj][3] * invl);
        *(uint2*)&out[obase + nj * 16 + quad * 4] = pk;
    }
}

// ---------------------------------------------------------------------------
extern "C" void kernel_launch(void* const* d_in, const int* in_sizes, int n_in,
                              void* d_out, int out_size, void* d_ws, size_t ws_size,
                              hipStream_t stream) {
    const float* x    = (const float*)d_in[0];
    const int*   pos  = (const int*)d_in[1];
    const float* Wqkv = (const float*)d_in[2];
    const float* Wout = (const float*)d_in[3];
    float*       out  = (float*)d_out;

    const int M = B_SZ * S_LEN;   // 4096

    u16* qkvb = (u16*)d_ws;                            // 4096 x 3072
    u16* aob  = qkvb + (size_t)M * 3 * D_MODEL;        // 4096 x 1024
    u16* xb   = aob  + (size_t)M * D_MODEL;            // 4096 x 1024
    u16* wqb  = xb   + (size_t)M * D_MODEL;            // 3072 x 1024
    u16* wob  = wqb  + (size_t)3 * D_MODEL * D_MODEL;  // 1024 x 1024
    u16* vtb  = wob  + (size_t)D_MODEL * D_MODEL;      // 4096 x 1024 (B,H,D,S)

    // 0) fused casts
    cast3_f32_bf16<<<(N1 + N2 + N3) / 256, 256, 0, stream>>>(x, Wqkv, Wout, xb, wqb, wob);

    // 1) qkv = x @ W_qkv^T
    gemm_bt_mfma<true><<<dim3(3 * D_MODEL / 128, M / 128), 256, 0, stream>>>(
        xb, wqb, qkvb, M, 3 * D_MODEL, D_MODEL);

    // 2) RoPE in place (Q scaled by 0.125*log2e)
    rope_bf16<<<(B_SZ * S_LEN * 2 * N_HEADS * 32) / 256, 256, 0, stream>>>(qkvb, pos);

    // 3) V transpose -> (B,H,D,S)
    vtrans<<<dim3(S_LEN / 64, N_HEADS, B_SZ), 256, 0, stream>>>(qkvb, vtb);

    // 4) MFMA flash attention -> aob (B,S,H*D) bf16
    attn_mfma<<<dim3(S_LEN / 64, N_HEADS, B_SZ), 256, 0, stream>>>(qkvb, vtb, aob);

    // 5) out = ao @ W_out^T (fp32 out)
    gemm_bt_mfma<false><<<dim3(D_MODEL / 128, M / 128), 256, 0, stream>>>(
        aob, wob, out, M, D_MODEL, D_MODEL);
}